// Round 1
// baseline (169.247 us; speedup 1.0000x reference)
//
#include <hip/hip_runtime.h>
#include <math.h>

// Fused MLP: x[32768,784] -> relu(x@w1^T+b1)[,128] -> relu(@w2^T+b2)[,256]
//            -> (@w3^T+b3)[,10] -> log_softmax
// fp32 everywhere (round 0: correctness baseline).
// Block = 256 threads handles BROWS=32 batch rows; all activations in LDS.

#define BROWS 32
#define TPB 256

__global__ __launch_bounds__(TPB, 2) void mnist_fused_f32(
    const float* __restrict__ x,   // [B,784]
    const float* __restrict__ w1,  // [128,784]
    const float* __restrict__ b1,  // [128]
    const float* __restrict__ w2,  // [256,128]
    const float* __restrict__ b2,  // [256]
    const float* __restrict__ w3,  // [10,256]
    const float* __restrict__ b3,  // [10]
    float* __restrict__ out)       // [B,10]
{
    __shared__ float s_stage[16 * 256];   // 16KB: w1-tile [16][128] / w2-tile [16][256] / w3 [10*256]
    __shared__ float s_xT[16][32];        // x tile, transposed [k][row]
    __shared__ float s_h1T[128][36];      // h1 transposed [c][row], pad to 36 (16B-aligned rows)
    __shared__ float s_h2T[256][36];      // h2 transposed [c][row]
    __shared__ float s_logits[BROWS][10];

    const int t    = threadIdx.x;
    const int row0 = blockIdx.x * BROWS;
    const int tc   = t & 31;   // 0..31  (col group)
    const int tr   = t >> 5;   // 0..7   (row group; rows tr*4 .. tr*4+3)

    // ---------------- Layer 1: h1[32][128] = relu(x @ w1^T + b1), K=784 tiled by 16
    float acc1[4][4];
    #pragma unroll
    for (int i = 0; i < 4; ++i)
        #pragma unroll
        for (int j = 0; j < 4; ++j) acc1[i][j] = 0.f;

    for (int kt = 0; kt < 49; ++kt) {
        const int k0 = kt * 16;
        __syncthreads();
        // stage x tile: 32 rows x 16 k, transposed -> s_xT[k][row]
        if (t < 128) {
            const int row = t >> 2, kq = t & 3;
            const float4 v = *reinterpret_cast<const float4*>(
                &x[(size_t)(row0 + row) * 784 + k0 + kq * 4]);
            s_xT[kq * 4 + 0][row] = v.x;
            s_xT[kq * 4 + 1][row] = v.y;
            s_xT[kq * 4 + 2][row] = v.z;
            s_xT[kq * 4 + 3][row] = v.w;
        }
        // stage w1 tile -> s_stage[kk*128 + n]
        #pragma unroll
        for (int f = 0; f < 2; ++f) {
            const int flat = f * 256 + t;        // 0..511
            const int n = flat & 127, kq = flat >> 7;
            const float4 v = *reinterpret_cast<const float4*>(
                &w1[(size_t)n * 784 + k0 + kq * 4]);
            s_stage[(kq * 4 + 0) * 128 + n] = v.x;
            s_stage[(kq * 4 + 1) * 128 + n] = v.y;
            s_stage[(kq * 4 + 2) * 128 + n] = v.z;
            s_stage[(kq * 4 + 3) * 128 + n] = v.w;
        }
        __syncthreads();
        #pragma unroll
        for (int kk = 0; kk < 16; ++kk) {
            const float4 a = *reinterpret_cast<const float4*>(&s_xT[kk][tr * 4]);
            const float4 b = *reinterpret_cast<const float4*>(&s_stage[kk * 128 + tc * 4]);
            const float av[4] = {a.x, a.y, a.z, a.w};
            const float bv[4] = {b.x, b.y, b.z, b.w};
            #pragma unroll
            for (int i = 0; i < 4; ++i)
                #pragma unroll
                for (int j = 0; j < 4; ++j)
                    acc1[i][j] = fmaf(av[i], bv[j], acc1[i][j]);
        }
    }
    // bias + relu -> s_h1T[c][r]
    {
        const float4 bb = *reinterpret_cast<const float4*>(&b1[tc * 4]);
        const float bbv[4] = {bb.x, bb.y, bb.z, bb.w};
        #pragma unroll
        for (int i = 0; i < 4; ++i) {
            const int r = tr * 4 + i;
            #pragma unroll
            for (int j = 0; j < 4; ++j) {
                const float h = acc1[i][j] + bbv[j];
                s_h1T[tc * 4 + j][r] = h > 0.f ? h : 0.f;
            }
        }
    }

    // ---------------- Layer 2: h2[32][256] = relu(h1 @ w2^T + b2), K=128 tiled by 16
    float acc2[4][8];
    #pragma unroll
    for (int i = 0; i < 4; ++i)
        #pragma unroll
        for (int j = 0; j < 8; ++j) acc2[i][j] = 0.f;

    for (int kt = 0; kt < 8; ++kt) {
        const int k0 = kt * 16;
        __syncthreads();   // also separates layer-1 h1T writes / s_stage reads
        // stage w2 tile -> s_stage[kk*256 + n]
        #pragma unroll
        for (int f = 0; f < 4; ++f) {
            const int flat = f * 256 + t;        // 0..1023
            const int n = flat & 255, kq = flat >> 8;
            const float4 v = *reinterpret_cast<const float4*>(
                &w2[(size_t)n * 128 + k0 + kq * 4]);
            s_stage[(kq * 4 + 0) * 256 + n] = v.x;
            s_stage[(kq * 4 + 1) * 256 + n] = v.y;
            s_stage[(kq * 4 + 2) * 256 + n] = v.z;
            s_stage[(kq * 4 + 3) * 256 + n] = v.w;
        }
        __syncthreads();
        #pragma unroll
        for (int kk = 0; kk < 16; ++kk) {
            const int kg = k0 + kk;
            const float4 a  = *reinterpret_cast<const float4*>(&s_h1T[kg][tr * 4]);
            const float4 bA = *reinterpret_cast<const float4*>(&s_stage[kk * 256 + tc * 4]);
            const float4 bB = *reinterpret_cast<const float4*>(&s_stage[kk * 256 + 128 + tc * 4]);
            const float av[4] = {a.x, a.y, a.z, a.w};
            const float bv[8] = {bA.x, bA.y, bA.z, bA.w, bB.x, bB.y, bB.z, bB.w};
            #pragma unroll
            for (int i = 0; i < 4; ++i)
                #pragma unroll
                for (int j = 0; j < 8; ++j)
                    acc2[i][j] = fmaf(av[i], bv[j], acc2[i][j]);
        }
    }
    // bias + relu -> s_h2T[c][r]; cols: c = tc*4 + (j&3) + 128*(j>>2)
    {
        const float4 bb0 = *reinterpret_cast<const float4*>(&b2[tc * 4]);
        const float4 bb1 = *reinterpret_cast<const float4*>(&b2[128 + tc * 4]);
        const float bbv[8] = {bb0.x, bb0.y, bb0.z, bb0.w, bb1.x, bb1.y, bb1.z, bb1.w};
        #pragma unroll
        for (int i = 0; i < 4; ++i) {
            const int r = tr * 4 + i;
            #pragma unroll
            for (int j = 0; j < 8; ++j) {
                const int c = tc * 4 + (j & 3) + 128 * (j >> 2);
                const float h = acc2[i][j] + bbv[j];
                s_h2T[c][r] = h > 0.f ? h : 0.f;
            }
        }
    }

    // ---------------- Layer 3: logits[32][10] = h2 @ w3^T + b3
    __syncthreads();                 // layer-2 done with s_stage; h2T visible after next barrier
    for (int q = t; q < 640; q += 256) {        // stage w3 (2560 floats)
        const float4 v = *reinterpret_cast<const float4*>(&w3[q * 4]);
        *reinterpret_cast<float4*>(&s_stage[q * 4]) = v;
    }
    __syncthreads();
    for (int idx = t; idx < 320; idx += 256) {  // 10 outputs x 32 rows
        const int o = idx >> 5, r = idx & 31;
        float acc = b3[o];
        #pragma unroll 8
        for (int c = 0; c < 256; ++c)
            acc = fmaf(s_h2T[c][r], s_stage[o * 256 + c], acc);
        s_logits[r][o] = acc;
    }
    __syncthreads();

    // ---------------- log_softmax + store
    if (t < BROWS) {
        float v[10];
        float m = -1e30f;
        #pragma unroll
        for (int o = 0; o < 10; ++o) { v[o] = s_logits[t][o]; m = fmaxf(m, v[o]); }
        float s = 0.f;
        #pragma unroll
        for (int o = 0; o < 10; ++o) s += expf(v[o] - m);
        const float ls = m + logf(s);
        float* op = &out[(size_t)(row0 + t) * 10];
        #pragma unroll
        for (int o = 0; o < 10; ++o) op[o] = v[o] - ls;
    }
}

extern "C" void kernel_launch(void* const* d_in, const int* in_sizes, int n_in,
                              void* d_out, int out_size, void* d_ws, size_t ws_size,
                              hipStream_t stream) {
    const float* x  = (const float*)d_in[0];
    const float* w1 = (const float*)d_in[1];
    const float* b1 = (const float*)d_in[2];
    const float* w2 = (const float*)d_in[3];
    const float* b2 = (const float*)d_in[4];
    const float* w3 = (const float*)d_in[5];
    const float* b3 = (const float*)d_in[6];
    float* out = (float*)d_out;

    const int B = 32768;
    dim3 grid(B / BROWS), block(TPB);
    mnist_fused_f32<<<grid, block, 0, stream>>>(x, w1, b1, w2, b2, w3, b3, out);
}

// Round 2
// 56.480 us; speedup vs baseline: 2.9966x; 2.9966x over previous
//
#include <hip/hip_runtime.h>
#include <math.h>

// Fused MLP via bf16 MFMA (fp32 accumulate):
//   x[32768,784] -> relu(x@w1^T+b1)[,128] -> relu(@w2^T+b2)[,256]
//   -> (@w3^T+b3)[,10->pad16] -> log_softmax
// Block = 256 threads (4 waves), 64 batch rows/block, 512 blocks (all resident).
// Weights converted fp32->bf16 per K-tile into shared staging buffer.
// All LDS tiles XOR-swizzled at 16B-slot granularity for conflict-free ds_read_b128.

#define TPB 256
#define BROWS 64

typedef __attribute__((ext_vector_type(8))) short bf16x8;
typedef __attribute__((ext_vector_type(4))) float f32x4;

static __device__ inline short f2bf(float f) {
    union { float f; unsigned u; } v; v.f = f;
    unsigned r = v.u + 0x7fffu + ((v.u >> 16) & 1u);   // RNE
    return (short)(r >> 16);
}

static __device__ inline bf16x8 cvt8(float4 a, float4 b) {
    bf16x8 r;
    r[0] = f2bf(a.x); r[1] = f2bf(a.y); r[2] = f2bf(a.z); r[3] = f2bf(a.w);
    r[4] = f2bf(b.x); r[5] = f2bf(b.y); r[6] = f2bf(b.z); r[7] = f2bf(b.w);
    return r;
}

__global__ __launch_bounds__(TPB, 2) void mnist_mfma_bf16(
    const float* __restrict__ x,   // [B,784]
    const float* __restrict__ w1,  // [128,784]
    const float* __restrict__ b1,  // [128]
    const float* __restrict__ w2,  // [256,128]
    const float* __restrict__ b2,  // [256]
    const float* __restrict__ w3,  // [10,256]
    const float* __restrict__ b3,  // [10]
    float* __restrict__ out)       // [B,10]
{
    // LDS: 16 + 4 + 16 + 32 = 68 KB -> 2 blocks/CU
    __shared__ __align__(16) short s_w[8192];    // weight tile staging (max [256][32] bf16)
    __shared__ __align__(16) short s_x[BROWS * 32];   // x K-tile  [64][32]
    __shared__ __align__(16) short s_h1[BROWS * 128]; // h1 bf16   [64][128]
    __shared__ __align__(16) short s_h2[BROWS * 256]; // h2 bf16   [64][256]

    const int t    = threadIdx.x;
    const int lane = t & 63;
    const int wv   = t >> 6;         // wave 0..3 -> M-tile rows 16*wv..+15
    const int l15  = lane & 15;
    const int l4   = lane >> 4;      // 0..3 (k-slot group)
    const int row0 = blockIdx.x * BROWS;

    const float4 fz = make_float4(0.f, 0.f, 0.f, 0.f);

    // ================= Layer 1: [64,784] x [784,128] =================
    f32x4 acc1[8];
    #pragma unroll
    for (int n = 0; n < 8; ++n) acc1[n] = (f32x4){0.f, 0.f, 0.f, 0.f};

    for (int kt = 0; kt < 25; ++kt) {           // K=784, 25 steps of 32 (last half-padded)
        const int k0 = kt * 32;
        __syncthreads();                         // WAR: previous compute done with s_x/s_w
        // stage x tile [64 rows][32 k] bf16, swizzled
        {
            const int r = t >> 2, s = t & 3;     // 64 rows x 4 slots
            const int kg = k0 + s * 8;
            float4 v0 = fz, v1 = fz;
            if (kg < 784) {
                const float* p = &x[(size_t)(row0 + r) * 784 + kg];
                v0 = *reinterpret_cast<const float4*>(p);
                v1 = *reinterpret_cast<const float4*>(p + 4);
            }
            *reinterpret_cast<bf16x8*>(&s_x[r * 32 + ((s ^ (r & 3)) << 3)]) = cvt8(v0, v1);
        }
        // stage w1 tile [128 rows][32 k] bf16, swizzled
        #pragma unroll
        for (int f = 0; f < 2; ++f) {
            const int q = f * 256 + t;           // 0..511
            const int n = q >> 2, s = q & 3;
            const int kg = k0 + s * 8;
            float4 v0 = fz, v1 = fz;
            if (kg < 784) {
                const float* p = &w1[(size_t)n * 784 + kg];
                v0 = *reinterpret_cast<const float4*>(p);
                v1 = *reinterpret_cast<const float4*>(p + 4);
            }
            *reinterpret_cast<bf16x8*>(&s_w[n * 32 + ((s ^ (n & 3)) << 3)]) = cvt8(v0, v1);
        }
        __syncthreads();
        // compute: A row = 16*wv + l15, k-slot = l4
        const bf16x8 a = *reinterpret_cast<const bf16x8*>(
            &s_x[(16 * wv + l15) * 32 + ((l4 ^ (l15 & 3)) << 3)]);
        #pragma unroll
        for (int n = 0; n < 8; ++n) {
            const bf16x8 b = *reinterpret_cast<const bf16x8*>(
                &s_w[(n * 16 + l15) * 32 + ((l4 ^ (l15 & 3)) << 3)]);
            acc1[n] = __builtin_amdgcn_mfma_f32_16x16x32_bf16(a, b, acc1[n], 0, 0, 0);
        }
    }
    // epilogue: bias + relu -> s_h1 [64][128] bf16 (swizzled, rowlen 128, 16 slots)
    #pragma unroll
    for (int n = 0; n < 8; ++n) {
        const int c  = n * 16 + l15;
        const float bc = b1[c];
        #pragma unroll
        for (int i = 0; i < 4; ++i) {
            const int r = 16 * wv + l4 * 4 + i;
            float h = acc1[n][i] + bc;
            h = h > 0.f ? h : 0.f;
            s_h1[r * 128 + (((c >> 3) ^ (r & 7)) << 3) + (c & 7)] = f2bf(h);
        }
    }

    // ================= Layer 2: [64,128] x [128,256] =================
    f32x4 acc2[16];
    #pragma unroll
    for (int n = 0; n < 16; ++n) acc2[n] = (f32x4){0.f, 0.f, 0.f, 0.f};

    for (int kt = 0; kt < 4; ++kt) {            // K=128, 4 steps
        const int k0 = kt * 32;
        __syncthreads();                         // h1 visible; s_w WAR safe
        // stage w2 tile [256 rows][32 k]
        #pragma unroll
        for (int f = 0; f < 4; ++f) {
            const int q = f * 256 + t;           // 0..1023
            const int n = q >> 2, s = q & 3;
            const int kg = k0 + s * 8;
            const float* p = &w2[(size_t)n * 128 + kg];
            const float4 v0 = *reinterpret_cast<const float4*>(p);
            const float4 v1 = *reinterpret_cast<const float4*>(p + 4);
            *reinterpret_cast<bf16x8*>(&s_w[n * 32 + ((s ^ (n & 3)) << 3)]) = cvt8(v0, v1);
        }
        __syncthreads();
        const bf16x8 a = *reinterpret_cast<const bf16x8*>(
            &s_h1[(16 * wv + l15) * 128 + (((((k0 >> 3) + l4)) ^ (l15 & 7)) << 3)]);
        #pragma unroll
        for (int n = 0; n < 16; ++n) {
            const bf16x8 b = *reinterpret_cast<const bf16x8*>(
                &s_w[(n * 16 + l15) * 32 + ((l4 ^ (l15 & 3)) << 3)]);
            acc2[n] = __builtin_amdgcn_mfma_f32_16x16x32_bf16(a, b, acc2[n], 0, 0, 0);
        }
    }
    // epilogue: bias + relu -> s_h2 [64][256] bf16 (rowlen 256, 32 slots)
    #pragma unroll
    for (int n = 0; n < 16; ++n) {
        const int c  = n * 16 + l15;
        const float bc = b2[c];
        #pragma unroll
        for (int i = 0; i < 4; ++i) {
            const int r = 16 * wv + l4 * 4 + i;
            float h = acc2[n][i] + bc;
            h = h > 0.f ? h : 0.f;
            s_h2[r * 256 + (((c >> 3) ^ (r & 7)) << 3) + (c & 7)] = f2bf(h);
        }
    }

    // ================= Layer 3: [64,256] x [256,16(pad)] =================
    __syncthreads();                             // s_w WAR vs layer-2 compute; h2 visible
    // stage w3 -> s_w as [16][256] bf16 (rows 10..15 zero), rowlen 256, 32 slots
    #pragma unroll
    for (int f = 0; f < 2; ++f) {
        const int q = f * 256 + t;               // 0..511
        const int n = q >> 5;                    // 0..15
        const int s = q & 31;                    // slot
        float4 v0 = fz, v1 = fz;
        if (n < 10) {
            const float* p = &w3[(size_t)n * 256 + s * 8];
            v0 = *reinterpret_cast<const float4*>(p);
            v1 = *reinterpret_cast<const float4*>(p + 4);
        }
        *reinterpret_cast<bf16x8*>(&s_w[n * 256 + ((s ^ (n & 7)) << 3)]) = cvt8(v0, v1);
    }
    __syncthreads();

    f32x4 acc3 = (f32x4){0.f, 0.f, 0.f, 0.f};
    #pragma unroll
    for (int kt = 0; kt < 8; ++kt) {            // K=256
        const int k0 = kt * 32;
        const int slot = ((k0 >> 3) + l4);
        const bf16x8 a = *reinterpret_cast<const bf16x8*>(
            &s_h2[(16 * wv + l15) * 256 + ((slot ^ (l15 & 7)) << 3)]);
        const bf16x8 b = *reinterpret_cast<const bf16x8*>(
            &s_w[l15 * 256 + ((slot ^ (l15 & 7)) << 3)]);
        acc3 = __builtin_amdgcn_mfma_f32_16x16x32_bf16(a, b, acc3, 0, 0, 0);
    }

    // bias + log_softmax + store. lane holds logits[16*wv + l4*4 + i][l15]
    const float b3c = (l15 < 10) ? b3[l15] : 0.f;
    #pragma unroll
    for (int i = 0; i < 4; ++i) {
        const float v = acc3[i] + b3c;
        float m = (l15 < 10) ? v : -1e30f;
        #pragma unroll
        for (int off = 8; off; off >>= 1) m = fmaxf(m, __shfl_xor(m, off, 16));
        const float e = (l15 < 10) ? expf(v - m) : 0.f;
        float sum = e;
        #pragma unroll
        for (int off = 8; off; off >>= 1) sum += __shfl_xor(sum, off, 16);
        const float ls = m + logf(sum);
        if (l15 < 10) {
            const int r = row0 + 16 * wv + l4 * 4 + i;
            out[(size_t)r * 10 + l15] = v - ls;
        }
    }
}

extern "C" void kernel_launch(void* const* d_in, const int* in_sizes, int n_in,
                              void* d_out, int out_size, void* d_ws, size_t ws_size,
                              hipStream_t stream) {
    const float* x  = (const float*)d_in[0];
    const float* w1 = (const float*)d_in[1];
    const float* b1 = (const float*)d_in[2];
    const float* w2 = (const float*)d_in[3];
    const float* b2 = (const float*)d_in[4];
    const float* w3 = (const float*)d_in[5];
    const float* b3 = (const float*)d_in[6];
    float* out = (float*)d_out;

    const int B = 32768;
    dim3 grid(B / BROWS), block(TPB);
    mnist_mfma_bf16<<<grid, block, 0, stream>>>(x, w1, b1, w2, b2, w3, b3, out);
}

// Round 3
// 35.959 us; speedup vs baseline: 4.7066x; 1.5707x over previous
//
#include <hip/hip_runtime.h>
#include <math.h>

// Fused MLP via bf16 MFMA, latency-optimized:
//   - 512-thread blocks (8 waves): wave = (mi = wv&3 -> 16-row M-tile, nh = wv>>2 -> N-half)
//   - T14 register prefetch: next K-tile's global loads issued under current MFMAs
//   - LDS union 40KB: {w-tile 16K | x-tile 4K | h1 16K} reused as {h2 32K | w3 8K} for layer 3
//   - K=32 tiles unswizzled (64B rows = natural 2-way, free); h1/h2/w3 XOR-swizzled
// grid 512 x 512thr -> 2 blocks/CU, 16 waves/CU.

#define TPB 512
#define BROWS 64

typedef __attribute__((ext_vector_type(8))) short bf16x8;
typedef __attribute__((ext_vector_type(4))) short bf16x4;
typedef __attribute__((ext_vector_type(4))) float f32x4;

static __device__ inline short f2bf(float f) {
    union { float f; unsigned u; } v; v.f = f;
    unsigned r = v.u + 0x7fffu + ((v.u >> 16) & 1u);   // RNE
    return (short)(r >> 16);
}
static __device__ inline bf16x4 cvt4(float4 a) {
    bf16x4 r; r[0]=f2bf(a.x); r[1]=f2bf(a.y); r[2]=f2bf(a.z); r[3]=f2bf(a.w); return r;
}
static __device__ inline bf16x8 cvt8(float4 a, float4 b) {
    bf16x8 r;
    r[0]=f2bf(a.x); r[1]=f2bf(a.y); r[2]=f2bf(a.z); r[3]=f2bf(a.w);
    r[4]=f2bf(b.x); r[5]=f2bf(b.y); r[6]=f2bf(b.z); r[7]=f2bf(b.w);
    return r;
}
static __device__ inline float4 ld4g(const float* p, bool ok) {
    return ok ? *reinterpret_cast<const float4*>(p) : make_float4(0.f, 0.f, 0.f, 0.f);
}

__global__ __launch_bounds__(TPB, 4) void mnist_mfma_v2(
    const float* __restrict__ x,   // [B,784]
    const float* __restrict__ w1,  // [128,784]
    const float* __restrict__ b1,  // [128]
    const float* __restrict__ w2,  // [256,128]
    const float* __restrict__ b2,  // [256]
    const float* __restrict__ w3,  // [10,256]
    const float* __restrict__ b3,  // [10]
    float* __restrict__ out)       // [B,10]
{
    __shared__ __align__(16) char smem[40 * 1024];
    short* const s_w  = (short*)(smem);               // [0,16K): w-tile (L1 [128][32], L2 [256][32])
    short* const s_x  = (short*)(smem + 16 * 1024);   // [16K,20K): x-tile [64][32]
    short* const s_h1 = (short*)(smem + 20 * 1024);   // [20K,36K): h1 [64][128] (swizzled)
    short* const s_h2 = (short*)(smem);               // [0,32K): h2 [64][256] (swizzled, layer 3)
    short* const s_w3 = (short*)(smem + 32 * 1024);   // [32K,40K): w3 [16][256] (swizzled)

    const int t    = threadIdx.x;
    const int lane = t & 63;
    const int wv   = t >> 6;          // 0..7
    const int mi   = wv & 3;          // M-tile (rows 16*mi..+15)
    const int nh   = wv >> 2;         // N-half
    const int l15  = lane & 15;
    const int l4   = lane >> 4;       // k-slot group
    const int row0 = blockIdx.x * BROWS;

    // staging index precompute
    const int xr = t >> 3, xs = t & 7;        // x: [64 rows][8 half-slots of 4]
    const int wn = t >> 2, ws = t & 3;        // w1: [128 rows][4 slots of 8]

    // ================= Layer 1: [64,784] x [784,128], K-tiles of 32 =================
    f32x4 acc1[4];
    #pragma unroll
    for (int f = 0; f < 4; ++f) acc1[f] = (f32x4){0.f, 0.f, 0.f, 0.f};

    // prologue loads (kt=0)
    float4 xa = ld4g(&x[(size_t)(row0 + xr) * 784 + xs * 4], true);
    float4 wa = ld4g(&w1[(size_t)wn * 784 + ws * 8], true);
    float4 wb = ld4g(&w1[(size_t)wn * 784 + ws * 8 + 4], true);

    for (int kt = 0; kt < 25; ++kt) {
        __syncthreads();                         // WAR: prior MFMAs done with s_x/s_w
        *reinterpret_cast<bf16x4*>(&s_x[xr * 32 + xs * 4]) = cvt4(xa);
        *reinterpret_cast<bf16x8*>(&s_w[wn * 32 + ws * 8]) = cvt8(wa, wb);
        if (kt < 24) {                           // prefetch kt+1 (in flight across barrier)
            const int k0 = (kt + 1) * 32;
            xa = ld4g(&x[(size_t)(row0 + xr) * 784 + k0 + xs * 4], k0 + xs * 4 < 784);
            const bool okw = k0 + ws * 8 < 784;
            wa = ld4g(&w1[(size_t)wn * 784 + k0 + ws * 8], okw);
            wb = ld4g(&w1[(size_t)wn * 784 + k0 + ws * 8 + 4], okw);
        }
        __syncthreads();
        const bf16x8 a = *reinterpret_cast<const bf16x8*>(&s_x[(16 * mi + l15) * 32 + l4 * 8]);
        #pragma unroll
        for (int f = 0; f < 4; ++f) {
            const bf16x8 b = *reinterpret_cast<const bf16x8*>(
                &s_w[(nh * 64 + f * 16 + l15) * 32 + l4 * 8]);
            acc1[f] = __builtin_amdgcn_mfma_f32_16x16x32_bf16(a, b, acc1[f], 0, 0, 0);
        }
    }

    // L1 epilogue: bias+relu -> s_h1 [64][128] swizzled (disjoint from s_x/s_w, no barrier)
    #pragma unroll
    for (int f = 0; f < 4; ++f) {
        const int c  = nh * 64 + f * 16 + l15;
        const float bc = b1[c];
        #pragma unroll
        for (int i = 0; i < 4; ++i) {
            const int r = 16 * mi + l4 * 4 + i;
            float h = acc1[f][i] + bc;
            h = h > 0.f ? h : 0.f;
            s_h1[r * 128 + ((((c >> 3) ^ (r & 7)) << 3) | (c & 7))] = f2bf(h);
        }
    }

    // ================= Layer 2: [64,128] x [128,256], 4 K-tiles =================
    f32x4 acc2[8];
    #pragma unroll
    for (int f = 0; f < 8; ++f) acc2[f] = (f32x4){0.f, 0.f, 0.f, 0.f};

    // prologue loads for w2 tile kt=0: [256 rows][4 slots], 2 per thread
    float4 w2a0 = ld4g(&w2[(size_t)(t >> 2) * 128 + (t & 3) * 8], true);
    float4 w2b0 = ld4g(&w2[(size_t)(t >> 2) * 128 + (t & 3) * 8 + 4], true);
    float4 w2a1 = ld4g(&w2[(size_t)(128 + (t >> 2)) * 128 + (t & 3) * 8], true);
    float4 w2b1 = ld4g(&w2[(size_t)(128 + (t >> 2)) * 128 + (t & 3) * 8 + 4], true);
    float4 w3a, w3b;

    for (int kt = 0; kt < 4; ++kt) {
        __syncthreads();                         // h1 visible; WAR on s_w
        *reinterpret_cast<bf16x8*>(&s_w[(t >> 2) * 32 + (t & 3) * 8]) = cvt8(w2a0, w2b0);
        *reinterpret_cast<bf16x8*>(&s_w[(128 + (t >> 2)) * 32 + (t & 3) * 8]) = cvt8(w2a1, w2b1);
        if (kt < 3) {
            const int k0 = (kt + 1) * 32;
            w2a0 = ld4g(&w2[(size_t)(t >> 2) * 128 + k0 + (t & 3) * 8], true);
            w2b0 = ld4g(&w2[(size_t)(t >> 2) * 128 + k0 + (t & 3) * 8 + 4], true);
            w2a1 = ld4g(&w2[(size_t)(128 + (t >> 2)) * 128 + k0 + (t & 3) * 8], true);
            w2b1 = ld4g(&w2[(size_t)(128 + (t >> 2)) * 128 + k0 + (t & 3) * 8 + 4], true);
        } else {
            // prefetch w3 [16][256] (rows >=10 zero), one 8-float slot per thread
            const int n3 = t >> 5, s3 = t & 31;
            const bool ok3 = n3 < 10;
            w3a = ld4g(&w3[(size_t)n3 * 256 + s3 * 8], ok3);
            w3b = ld4g(&w3[(size_t)n3 * 256 + s3 * 8 + 4], ok3);
        }
        __syncthreads();
        const bf16x8 a = *reinterpret_cast<const bf16x8*>(
            &s_h1[(16 * mi + l15) * 128 + (((kt * 4 + l4) ^ (l15 & 7)) << 3)]);
        #pragma unroll
        for (int f = 0; f < 8; ++f) {
            const bf16x8 b = *reinterpret_cast<const bf16x8*>(
                &s_w[(nh * 128 + f * 16 + l15) * 32 + l4 * 8]);
            acc2[f] = __builtin_amdgcn_mfma_f32_16x16x32_bf16(a, b, acc2[f], 0, 0, 0);
        }
    }

    // ================= Layer 3 setup: h2 + w3 into union region =================
    __syncthreads();                             // all L2 MFMAs done before overwriting region
    #pragma unroll
    for (int f = 0; f < 8; ++f) {
        const int c  = nh * 128 + f * 16 + l15;
        const float bc = b2[c];
        #pragma unroll
        for (int i = 0; i < 4; ++i) {
            const int r = 16 * mi + l4 * 4 + i;
            float h = acc2[f][i] + bc;
            h = h > 0.f ? h : 0.f;
            s_h2[r * 256 + ((((c >> 3) ^ (r & 7)) << 3) | (c & 7))] = f2bf(h);
        }
    }
    {
        const int n3 = t >> 5, s3 = t & 31;
        *reinterpret_cast<bf16x8*>(&s_w3[n3 * 256 + ((s3 ^ (n3 & 7)) << 3)]) = cvt8(w3a, w3b);
    }
    __syncthreads();

    // ================= Layer 3 (nh==0 waves): [64,256] x [256,16] + log_softmax ====
    if (nh == 0) {
        f32x4 acc3 = (f32x4){0.f, 0.f, 0.f, 0.f};
        #pragma unroll
        for (int kt = 0; kt < 8; ++kt) {
            const int slot = kt * 4 + l4;
            const bf16x8 a = *reinterpret_cast<const bf16x8*>(
                &s_h2[(16 * mi + l15) * 256 + ((slot ^ (l15 & 7)) << 3)]);
            const bf16x8 b = *reinterpret_cast<const bf16x8*>(
                &s_w3[l15 * 256 + ((slot ^ (l15 & 7)) << 3)]);
            acc3 = __builtin_amdgcn_mfma_f32_16x16x32_bf16(a, b, acc3, 0, 0, 0);
        }
        const float b3c = (l15 < 10) ? b3[l15] : 0.f;
        #pragma unroll
        for (int i = 0; i < 4; ++i) {
            const float v = acc3[i] + b3c;
            float m = (l15 < 10) ? v : -1e30f;
            #pragma unroll
            for (int off = 8; off; off >>= 1) m = fmaxf(m, __shfl_xor(m, off, 16));
            const float e = (l15 < 10) ? expf(v - m) : 0.f;
            float sum = e;
            #pragma unroll
            for (int off = 8; off; off >>= 1) sum += __shfl_xor(sum, off, 16);
            const float ls = m + logf(sum);
            if (l15 < 10) {
                const int r = row0 + 16 * mi + l4 * 4 + i;
                out[(size_t)r * 10 + l15] = v - ls;
            }
        }
    }
}

extern "C" void kernel_launch(void* const* d_in, const int* in_sizes, int n_in,
                              void* d_out, int out_size, void* d_ws, size_t ws_size,
                              hipStream_t stream) {
    const float* x  = (const float*)d_in[0];
    const float* w1 = (const float*)d_in[1];
    const float* b1 = (const float*)d_in[2];
    const float* w2 = (const float*)d_in[3];
    const float* b2 = (const float*)d_in[4];
    const float* w3 = (const float*)d_in[5];
    const float* b3 = (const float*)d_in[6];
    float* out = (float*)d_out;

    const int B = 32768;
    dim3 grid(B / BROWS), block(TPB);
    mnist_mfma_v2<<<grid, block, 0, stream>>>(x, w1, b1, w2, b2, w3, b3, out);
}